// Round 1
// baseline (231.948 us; speedup 1.0000x reference)
//
#include <hip/hip_runtime.h>
#include <math.h>

#define B_ 128
#define S_ 1024
#define D_ 256          // D == A == O == 256
#define VP 264          // bf16 row pitch for wave-private v buffer (528 B)
#define TP 68           // f32 row pitch for transpose buffer (272 B)
#define WB 8576         // per-wave LDS bytes: v buf 16*VP*2 = 8448, + rev/rrs 128
#define ORED_OFF 4352   // f32 [4][256] out-partials, aliases tail of v buf (after trans region)
#define RED_OFF  8448   // rev[16] + rrs[16]

using bf16x8 = __attribute__((ext_vector_type(8))) __bf16;
using f32x4  = __attribute__((ext_vector_type(4))) float;

__device__ __forceinline__ float qred_add(float v) {   // reduce across 16-lane group
    v += __shfl_xor(v, 1); v += __shfl_xor(v, 2);
    v += __shfl_xor(v, 4); v += __shfl_xor(v, 8);
    return v;
}
__device__ __forceinline__ float wred_add(float x) {
#pragma unroll
    for (int off = 32; off > 0; off >>= 1) x += __shfl_xor(x, off, 64);
    return x;
}

// ---- prep: pack W, Uo (fp32 row-major [k][n]) into B-fragment-linear bf16.
__global__ __launch_bounds__(256) void k_prep(
    const float* __restrict__ W, const float* __restrict__ Uo,
    __bf16* __restrict__ Wf, __bf16* __restrict__ Uf)
{
    const int e = blockIdx.x * 256 + threadIdx.x;   // 0..65535
    const int frag = e >> 9, rem = e & 511;
    const int lane = rem >> 3, j = rem & 7;
    const int kk = frag >> 4, tn = frag & 15;
    const int k = kk * 32 + (lane >> 4) * 8 + j;
    const int n = tn * 16 + (lane & 15);
    Wf[e] = (__bf16)W[k * 256 + n];
    Uf[e] = (__bf16)Uo[k * 256 + n];
}

// ---- main fused kernel: each wave owns 16 rows x 256 cols, fully independent.
// Block = 4 waves = 64 rows; only barrier is the final out-partial reduce.
__global__ __launch_bounds__(256, 4) void k_rows(
    const float* __restrict__ x, const float* __restrict__ mask,
    const __bf16* __restrict__ Wf, const float* __restrict__ bo,
    const float* __restrict__ u, const __bf16* __restrict__ Uf,
    float* __restrict__ e_out,    // [B*S] unnormalized exp(vu)*mask (alphas region)
    float* __restrict__ betas,    // [B*S, 256]
    float* __restrict__ outraw)   // [B,256] atomic accumulator (pre-zeroed)
{
    __shared__ __align__(16) char smem[4 * WB];
    const int tid = threadIdx.x, lane = tid & 63, w = tid >> 6;
    const int hi = lane >> 4, c = lane & 15;
    char* wbase = smem + w * WB;
    __bf16* vb  = (__bf16*)wbase;                // [16][VP] bf16 v tile (wave-private)
    float* tw   = (float*)wbase;                 // [16][TP] f32 transpose buf (alias)
    float* ored = (float*)(wbase + ORED_OFF);    // [4][256] out partials
    float* rev  = (float*)(wbase + RED_OFF);     // [16] exp(vu)*mask per row
    float* rrs  = rev + 16;                      // [16] 1/beta-rowsum per row

    const int row0 = (blockIdx.x * 4 + w) * 16;
    const bf16x8* Wf8 = (const bf16x8*)Wf;
    const bf16x8* Uf8 = (const bf16x8*)Uf;

    // ---- A-fragments: x rows direct from global, f32 -> bf16 in-register.
    // A-frag layout (16x16x32): row = lane&15, k = (lane>>4)*8 + j
    const float* xw = x + (size_t)(row0 + c) * D_;
    bf16x8 a[8];
#pragma unroll
    for (int kk = 0; kk < 8; ++kk) {
        const float4 t0 = *(const float4*)(xw + kk * 32 + hi * 8);
        const float4 t1 = *(const float4*)(xw + kk * 32 + hi * 8 + 4);
        bf16x8 h;
        h[0] = (__bf16)t0.x; h[1] = (__bf16)t0.y; h[2] = (__bf16)t0.z; h[3] = (__bf16)t0.w;
        h[4] = (__bf16)t1.x; h[5] = (__bf16)t1.y; h[6] = (__bf16)t1.z; h[7] = (__bf16)t1.w;
        a[kk] = h;
    }

    float mk4[4];   // mask per row hi*4+r (16-lane broadcast loads)
#pragma unroll
    for (int r = 0; r < 4; ++r) mk4[r] = mask[row0 + hi * 4 + r];

    // ---- GEMM1: t = x @ W  (wave computes its 16 rows x all 256 cols)
    f32x4 acc[16];
#pragma unroll
    for (int j = 0; j < 16; ++j) acc[j] = (f32x4){0.f, 0.f, 0.f, 0.f};
#pragma unroll
    for (int kk = 0; kk < 8; ++kk) {
#pragma unroll
        for (int j = 0; j < 16; ++j) {
            const bf16x8 b = Wf8[(kk * 16 + j) * 64 + lane];
            acc[j] = __builtin_amdgcn_mfma_f32_16x16x32_bf16(a[kk], b, acc[j], 0, 0, 0);
        }
    }

    // bias + row sum-of-squares -> inv norm (wave-local: 16-lane qred, in-register)
#pragma unroll
    for (int j = 0; j < 16; ++j) {
        const float bj = bo[j * 16 + c];
#pragma unroll
        for (int r = 0; r < 4; ++r) acc[j][r] += bj;
    }
    float inv_[4];
#pragma unroll
    for (int r = 0; r < 4; ++r) {
        float s = 0.f;
#pragma unroll
        for (int j = 0; j < 16; ++j) s += acc[j][r] * acc[j][r];
        s = qred_add(s);
        inv_[r] = 1.f / fmaxf(sqrtf(s), 1e-12f);
    }

    // v = tanh(t/||t||): write v (bf16) to wave-private LDS, accumulate vu partials
    float vup[4] = {0.f, 0.f, 0.f, 0.f};
#pragma unroll
    for (int j = 0; j < 16; ++j) {
        const float uj = u[j * 16 + c];
#pragma unroll
        for (int r = 0; r < 4; ++r) {
            const float tv = acc[j][r] * inv_[r];
            const float e2 = __expf(2.f * tv);
            const float v  = (e2 - 1.f) * __frcp_rn(e2 + 1.f);
            vup[r] += v * uj;
            vb[(hi * 4 + r) * VP + j * 16 + c] = (__bf16)v;
        }
    }
#pragma unroll
    for (int r = 0; r < 4; ++r) {
        const float vu  = qred_add(vup[r]);
        const float evr = __expf(vu) * mk4[r];
        if (c == r) { rev[hi * 4 + r] = evr; e_out[row0 + hi * 4 + r] = evr; }
    }

    // ---- GEMM2: vuo = v @ Uo (a-frags from wave-private LDS; compiler orders lgkmcnt)
    f32x4 vo[16];
#pragma unroll
    for (int j = 0; j < 16; ++j) vo[j] = (f32x4){0.f, 0.f, 0.f, 0.f};
#pragma unroll
    for (int kk = 0; kk < 8; ++kk) {
        const bf16x8 av = *(const bf16x8*)(vb + c * VP + kk * 32 + hi * 8);
#pragma unroll
        for (int j = 0; j < 16; ++j) {
            const bf16x8 b = Uf8[(kk * 16 + j) * 64 + lane];
            vo[j] = __builtin_amdgcn_mfma_f32_16x16x32_bf16(av, b, vo[j], 0, 0, 0);
        }
    }

    // betas numerator: exp(vuo*mask)*mask (no max shift: |vuo|<=~5, ratio exact)
    float psum[4] = {0.f, 0.f, 0.f, 0.f};
#pragma unroll
    for (int j = 0; j < 16; ++j)
#pragma unroll
        for (int r = 0; r < 4; ++r) {
            const float e = __expf(vo[j][r] * mk4[r]) * mk4[r];
            vo[j][r] = e;
            psum[r] += e;
        }
#pragma unroll
    for (int r = 0; r < 4; ++r) {
        const float s   = qred_add(psum[r]);
        const float rsv = 1.f / ((s == 0.f) ? 1.f : s);
        if (c == r) rrs[hi * 4 + r] = rsv;
    }

    // ---- epilogue: per-wave LDS transpose -> coalesced nontemporal f32x4 stores,
    //      fused out-partials with x re-read (L2-hot).
    asm volatile("s_waitcnt lgkmcnt(0)" ::: "memory");   // rev/rrs writes + GEMM2 reads drained
    float evp[4], rsp[4];
#pragma unroll
    for (int p = 0; p < 4; ++p) { evp[p] = rev[hi + p * 4]; rsp[p] = rrs[hi + p * 4]; }

    const float* xr = x + (size_t)row0 * D_;
#pragma unroll
    for (int ch = 0; ch < 4; ++ch) {
        asm volatile("s_waitcnt lgkmcnt(0)" ::: "memory");  // WAR: prior trans/v reads done
#pragma unroll
        for (int jj = 0; jj < 4; ++jj)
#pragma unroll
            for (int r = 0; r < 4; ++r)
                tw[(hi * 4 + r) * TP + jj * 16 + c] = vo[ch * 4 + jj][r];
        asm volatile("s_waitcnt lgkmcnt(0)" ::: "memory");  // RAW: writes visible
        f32x4 op = (f32x4){0.f, 0.f, 0.f, 0.f};
#pragma unroll
        for (int p = 0; p < 4; ++p) {
            const int rl = hi + p * 4;
            f32x4 b4 = *(const f32x4*)&tw[rl * TP + c * 4];
            const float rsv = rsp[p];
            b4[0] *= rsv; b4[1] *= rsv; b4[2] *= rsv; b4[3] *= rsv;
            const size_t goff = (size_t)(row0 + rl) * D_ + ch * 64 + c * 4;
            __builtin_nontemporal_store(b4, (f32x4*)&betas[goff]);  // 256 B/16-lane group
            const float evv = evp[p];
            if (evv != 0.f) {                                // 16-lane-uniform skip
                const f32x4 x4 = *(const f32x4*)&xr[rl * D_ + ch * 64 + c * 4];
                op[0] += evv * b4[0] * x4[0];
                op[1] += evv * b4[1] * x4[1];
                op[2] += evv * b4[2] * x4[2];
                op[3] += evv * b4[3] * x4[3];
            }
        }
        *(f32x4*)&ored[hi * 256 + ch * 64 + c * 4] = op;
    }

    // single end-of-kernel barrier: block-reduce out partials, 1 atomic/col/block
    __syncthreads();
    {
        float o = 0.f;
#pragma unroll
        for (int ww = 0; ww < 4; ++ww) {
            const float* orw = (const float*)(smem + ww * WB + ORED_OFF);
#pragma unroll
            for (int h2 = 0; h2 < 4; ++h2) o += orw[h2 * 256 + tid];
        }
        const int b = row0 >> 10;    // all 64 rows of the block share one batch
        atomicAdd(&outraw[b * D_ + tid], o);
    }
}

// ---- final: Z per batch, normalize alphas in place, scale out.
__global__ __launch_bounds__(256) void k_fin(
    float* __restrict__ e_alphas, float* __restrict__ out)
{
    const int b = blockIdx.x;
    const int tid = threadIdx.x, lane = tid & 63, wid = tid >> 6;
    __shared__ float red[4];
    const int base = b * S_;
    float ev[4];
#pragma unroll
    for (int k = 0; k < 4; ++k) ev[k] = e_alphas[base + tid + 256 * k];
    float s = ev[0] + ev[1] + ev[2] + ev[3];
    s = wred_add(s);
    if (lane == 0) red[wid] = s;
    __syncthreads();
    const float Z = red[0] + red[1] + red[2] + red[3];
    const float Zr = 1.f / ((Z == 0.f) ? 1.f : Z);
#pragma unroll
    for (int k = 0; k < 4; ++k) e_alphas[base + tid + 256 * k] = ev[k] * Zr;
    out[b * D_ + tid] *= Zr;
}

extern "C" void kernel_launch(void* const* d_in, const int* in_sizes, int n_in,
                              void* d_out, int out_size, void* d_ws, size_t ws_size,
                              hipStream_t stream) {
    const float* x    = (const float*)d_in[0];
    const float* mask = (const float*)d_in[1];
    const float* W    = (const float*)d_in[2];
    const float* bo   = (const float*)d_in[3];
    const float* u    = (const float*)d_in[4];
    const float* Uo   = (const float*)d_in[5];

    float* out    = (float*)d_out;             // [B, 256]
    float* alphas = out + B_ * D_;             // [B, S]
    float* betas  = alphas + (size_t)B_ * S_;  // [B, S, 256]

    __bf16* Wf = (__bf16*)d_ws;                // 128 KB
    __bf16* Uf = Wf + 65536;                   // 128 KB

    hipMemsetAsync(out, 0, (size_t)B_ * D_ * sizeof(float), stream);
    k_prep<<<256, 256, 0, stream>>>(W, Uo, Wf, Uf);
    k_rows<<<B_ * S_ / 64, 256, 0, stream>>>(x, mask, Wf, bo, u, Uf, alphas, betas, out);
    k_fin <<<B_, 256, 0, stream>>>(alphas, out);
}

// Round 2
// 104.859 us; speedup vs baseline: 2.2120x; 2.2120x over previous
//
#include <hip/hip_runtime.h>
#include <math.h>

#define B_ 128
#define S_ 1024
#define D_ 256          // D == A == O == 256
#define XP 264          // LDS bf16 row pitch for x/v tile (528 B, 16B-aligned)
#define TP 68           // LDS fp32 row pitch for transpose buffer (272 B, 16B-aligned)
#define ROWS 32         // rows per block

using bf16x8 = __attribute__((ext_vector_type(8))) __bf16;
using bf16x4 = __attribute__((ext_vector_type(4))) __bf16;
using f32x4  = __attribute__((ext_vector_type(4))) float;

__device__ __forceinline__ float qred_add(float v) {   // reduce across 16-lane group
    v += __shfl_xor(v, 1); v += __shfl_xor(v, 2);
    v += __shfl_xor(v, 4); v += __shfl_xor(v, 8);
    return v;
}
__device__ __forceinline__ float wred_add(float x) {
#pragma unroll
    for (int off = 32; off > 0; off >>= 1) x += __shfl_xor(x, off, 64);
    return x;
}

// ---- prep: pack W, Uo (fp32 row-major [k][n]) into B-fragment-linear bf16.
__global__ __launch_bounds__(256) void k_prep(
    const float* __restrict__ W, const float* __restrict__ Uo,
    __bf16* __restrict__ Wf, __bf16* __restrict__ Uf)
{
    const int e = blockIdx.x * 256 + threadIdx.x;   // 0..65535
    const int frag = e >> 9, rem = e & 511;
    const int lane = rem >> 3, j = rem & 7;
    const int kk = frag >> 4, tn = frag & 15;
    const int k = kk * 32 + (lane >> 4) * 8 + j;
    const int n = tn * 16 + (lane & 15);
    Wf[e] = (__bf16)W[k * 256 + n];
    Uf[e] = (__bf16)Uo[k * 256 + n];
}

// ---- main fused kernel: 32 rows/block, 4 waves; wave w owns cols [64w, 64w+64).
// launch_bounds(256,3): ~170-reg budget -> no scratch spill (round-0's (256,4)
// capped at 128 unified and spilled ~112 B/thread = +115 MB HBM writes).
__global__ __launch_bounds__(256, 3) void k_rows(
    const float* __restrict__ x, const float* __restrict__ mask,
    const __bf16* __restrict__ Wf, const float* __restrict__ bo,
    const float* __restrict__ u, const __bf16* __restrict__ Uf,
    float* __restrict__ e_out,    // [B*S] unnormalized exp(vu)*mask (alphas region)
    float* __restrict__ betas,    // [B*S, 256]
    float* __restrict__ part,     // [gridDim.x, 256] per-block out partials (ws)
    float* __restrict__ outraw,   // [B,256] atomic fallback accumulator
    const int use_part)
{
    // xs (bf16 x/v tile, 16896 B) aliased with trans (fp32 transpose buf, 17408 B)
    __shared__ __align__(16) char smem[4 * 16 * TP * 4];
    __bf16* xs   = (__bf16*)smem;
    float* trans = (float*)smem;
    __shared__ float red[4][ROWS];
    const int tid = threadIdx.x, lane = tid & 63, w = tid >> 6;
    const int quad = lane >> 4, c = lane & 15;
    const int hi = lane >> 4, c4 = lane & 15;      // store-phase decomposition
    const int row0 = blockIdx.x * ROWS;
    const bf16x8* Wf8 = (const bf16x8*)Wf;
    const bf16x8* Uf8 = (const bf16x8*)Uf;

    // stage x[32][256] fp32 -> bf16 LDS
    {
        const float4* xg = (const float4*)(x + (size_t)row0 * D_);
#pragma unroll
        for (int it = 0; it < 8; ++it) {
            const int r = it * 4 + w;
            const float4 t = xg[r * 64 + lane];
            bf16x4 h; h[0] = (__bf16)t.x; h[1] = (__bf16)t.y; h[2] = (__bf16)t.z; h[3] = (__bf16)t.w;
            *(bf16x4*)(xs + r * XP + lane * 4) = h;
        }
    }

    __syncthreads();                                   // sync0

    // ---- GEMM1: t = x @ W
    f32x4 acc[2][4];
#pragma unroll
    for (int i = 0; i < 2; ++i)
#pragma unroll
        for (int j = 0; j < 4; ++j) acc[i][j] = (f32x4){0.f, 0.f, 0.f, 0.f};
#pragma unroll
    for (int kk = 0; kk < 8; ++kk) {
        bf16x8 a[2], b[4];
#pragma unroll
        for (int i = 0; i < 2; ++i)
            a[i] = *(const bf16x8*)(xs + (i * 16 + c) * XP + kk * 32 + quad * 8);
#pragma unroll
        for (int j = 0; j < 4; ++j)
            b[j] = Wf8[(kk * 16 + w * 4 + j) * 64 + lane];
#pragma unroll
        for (int i = 0; i < 2; ++i)
#pragma unroll
            for (int j = 0; j < 4; ++j)
                acc[i][j] = __builtin_amdgcn_mfma_f32_16x16x32_bf16(a[i], b[j], acc[i][j], 0, 0, 0);
    }

    // bias + row sum-of-squares partials
#pragma unroll
    for (int j = 0; j < 4; ++j) {
        const float bj = bo[w * 64 + j * 16 + c];
#pragma unroll
        for (int i = 0; i < 2; ++i)
#pragma unroll
            for (int r = 0; r < 4; ++r) acc[i][j][r] += bj;
    }
    {
        float myv = 0.f;
#pragma unroll
        for (int i = 0; i < 2; ++i)
#pragma unroll
            for (int r = 0; r < 4; ++r) {
                float s = 0.f;
#pragma unroll
                for (int j = 0; j < 4; ++j) s += acc[i][j][r] * acc[i][j][r];
                const float p = qred_add(s);
                if (c == i * 4 + r) myv = p;
            }
        if (c < 8) red[w][(c >> 2) * 16 + quad * 4 + (c & 3)] = myv;
    }
    __syncthreads();                                   // (a)

    float inv[2][4];
#pragma unroll
    for (int i = 0; i < 2; ++i)
#pragma unroll
        for (int r = 0; r < 4; ++r) {
            const int row = i * 16 + quad * 4 + r;
            const float t = red[0][row] + red[1][row] + red[2][row] + red[3][row];
            inv[i][r] = 1.f / fmaxf(sqrtf(t), 1e-12f);
        }

    // v = tanh(t/||t||): vu partials, write v (bf16) into xs (reuse)
    float uj[4];
#pragma unroll
    for (int j = 0; j < 4; ++j) uj[j] = u[w * 64 + j * 16 + c];
    float vup[2][4];
#pragma unroll
    for (int i = 0; i < 2; ++i)
#pragma unroll
        for (int r = 0; r < 4; ++r) vup[i][r] = 0.f;
#pragma unroll
    for (int i = 0; i < 2; ++i)
#pragma unroll
        for (int j = 0; j < 4; ++j)
#pragma unroll
            for (int r = 0; r < 4; ++r) {
                const float tv = acc[i][j][r] * inv[i][r];
                const float e2 = __expf(2.f * tv);
                const float v  = (e2 - 1.f) * __frcp_rn(e2 + 1.f);
                vup[i][r] += v * uj[j];
                xs[(i * 16 + quad * 4 + r) * XP + (w * 64 + j * 16 + c)] = (__bf16)v;
            }
    __syncthreads();                                   // (b) R1 reads + v writes done
    {
        float myv = 0.f;
#pragma unroll
        for (int i = 0; i < 2; ++i)
#pragma unroll
            for (int r = 0; r < 4; ++r) {
                const float p = qred_add(vup[i][r]);
                if (c == i * 4 + r) myv = p;
            }
        if (c < 8) red[w][(c >> 2) * 16 + quad * 4 + (c & 3)] = myv;
    }
    __syncthreads();                                   // (c) vu available in red

    // ev in store mapping: row r_ip = i*16 + hi + p*4
    float ev[2][4];
#pragma unroll
    for (int i = 0; i < 2; ++i)
#pragma unroll
        for (int p = 0; p < 4; ++p) {
            const int rr = i * 16 + hi + p * 4;
            const float vu = red[0][rr] + red[1][rr] + red[2][rr] + red[3][rr];
            ev[i][p] = __expf(vu) * mask[row0 + rr];
        }
    if (tid < ROWS) {
        const float vu = red[0][tid] + red[1][tid] + red[2][tid] + red[3][tid];
        e_out[row0 + tid] = __expf(vu) * mask[row0 + tid];
    }

    // ---- GEMM2: vuo = v @ Uo
    f32x4 vo[2][4];
#pragma unroll
    for (int i = 0; i < 2; ++i)
#pragma unroll
        for (int j = 0; j < 4; ++j) vo[i][j] = (f32x4){0.f, 0.f, 0.f, 0.f};
#pragma unroll
    for (int kk = 0; kk < 8; ++kk) {
        bf16x8 a[2], b[4];
#pragma unroll
        for (int i = 0; i < 2; ++i)
            a[i] = *(const bf16x8*)(xs + (i * 16 + c) * XP + kk * 32 + quad * 8);
#pragma unroll
        for (int j = 0; j < 4; ++j)
            b[j] = Uf8[(kk * 16 + w * 4 + j) * 64 + lane];
#pragma unroll
        for (int i = 0; i < 2; ++i)
#pragma unroll
            for (int j = 0; j < 4; ++j)
                vo[i][j] = __builtin_amdgcn_mfma_f32_16x16x32_bf16(a[i], b[j], vo[i][j], 0, 0, 0);
    }

    // betas numerator: exp(vuo*mask)*mask  (no max shift: |vuo| <= ~10, cancels exactly)
    // mk loaded HERE (its only use) -- not held across the whole first half.
    float mk[2][4];
#pragma unroll
    for (int i = 0; i < 2; ++i)
#pragma unroll
        for (int r = 0; r < 4; ++r) mk[i][r] = mask[row0 + i * 16 + quad * 4 + r];
#pragma unroll
    for (int i = 0; i < 2; ++i)
#pragma unroll
        for (int j = 0; j < 4; ++j)
#pragma unroll
            for (int r = 0; r < 4; ++r) {
                const float t = vo[i][j][r] * mk[i][r];
                vo[i][j][r] = __expf(t) * mk[i][r];
            }
    // row sums
    float psum[2][4];
#pragma unroll
    for (int i = 0; i < 2; ++i)
#pragma unroll
        for (int r = 0; r < 4; ++r) {
            float s = 0.f;
#pragma unroll
            for (int j = 0; j < 4; ++j) s += vo[i][j][r];
            psum[i][r] = s;
        }
    __syncthreads();                                   // (d') ev/red reads + GEMM2 xs reads done
    {
        float myv = 0.f;
#pragma unroll
        for (int i = 0; i < 2; ++i)
#pragma unroll
            for (int r = 0; r < 4; ++r) {
                const float p = qred_add(psum[i][r]);
                if (c == i * 4 + r) myv = p;
            }
        if (c < 8) red[w][(c >> 2) * 16 + quad * 4 + (c & 3)] = myv;
    }
    __syncthreads();                                   // (e') beta sums in red

    // rs in store mapping
    float rs[2][4];
#pragma unroll
    for (int i = 0; i < 2; ++i)
#pragma unroll
        for (int p = 0; p < 4; ++p) {
            const int rr = i * 16 + hi + p * 4;
            const float s = red[0][rr] + red[1][rr] + red[2][rr] + red[3][rr];
            rs[i][p] = 1.f / ((s == 0.f) ? 1.f : s);
        }

    // ---- epilogue: LDS transpose (wave-private slice) -> coalesced float4 stores,
    //      fused out-partials with coalesced masked x re-read.
    float* tw = trans + w * (16 * TP);
    f32x4 opart = (f32x4){0.f, 0.f, 0.f, 0.f};
#pragma unroll
    for (int i = 0; i < 2; ++i) {
        asm volatile("s_waitcnt lgkmcnt(0)" ::: "memory");  // prior trans reads drained (WAR)
#pragma unroll
        for (int j = 0; j < 4; ++j)
#pragma unroll
            for (int r = 0; r < 4; ++r)
                tw[(quad * 4 + r) * TP + j * 16 + c] = vo[i][j][r];
        asm volatile("s_waitcnt lgkmcnt(0)" ::: "memory");  // writes visible (RAW)
#pragma unroll
        for (int p = 0; p < 4; ++p) {
            const int rl = hi + p * 4;                      // local row 0..15
            f32x4 b4 = *(const f32x4*)&tw[rl * TP + c4 * 4];
            const float rsv = rs[i][p];
            b4[0] *= rsv; b4[1] *= rsv; b4[2] *= rsv; b4[3] *= rsv;
            const size_t goff = (size_t)(row0 + i * 16 + rl) * D_ + w * 64 + c4 * 4;
            __builtin_nontemporal_store(b4, (f32x4*)&betas[goff]); // never re-read: keep L2 for x
            const float evv = ev[i][p];
            if (evv != 0.f) {                               // 16-lane-uniform skip
                const f32x4 x4 = *(const f32x4*)&x[goff];
                opart[0] += evv * b4[0] * x4[0];
                opart[1] += evv * b4[1] * x4[1];
                opart[2] += evv * b4[2] * x4[2];
                opart[3] += evv * b4[3] * x4[3];
            }
        }
    }
    // reduce across the 4 row-groups
#pragma unroll
    for (int k = 0; k < 4; ++k) {
        opart[k] += __shfl_xor(opart[k], 16);
        opart[k] += __shfl_xor(opart[k], 32);
    }
    if (lane < 16) {
        const int col = w * 64 + c4 * 4;
        if (use_part) {
            *(f32x4*)&part[(size_t)blockIdx.x * D_ + col] = opart;
        } else {
            const int b = row0 >> 10;
#pragma unroll
            for (int k = 0; k < 4; ++k) atomicAdd(&outraw[b * D_ + col + k], opart[k]);
        }
    }
}

// ---- final: Z per batch, normalize alphas in place, reduce out partials.
__global__ __launch_bounds__(256) void k_fin(
    const float* __restrict__ part, float* __restrict__ e_alphas,
    float* __restrict__ out, const int use_part)
{
    const int b = blockIdx.x;
    const int tid = threadIdx.x, lane = tid & 63, wid = tid >> 6;
    __shared__ float red[4];
    const int base = b * S_;
    float ev[4];
#pragma unroll
    for (int k = 0; k < 4; ++k) ev[k] = e_alphas[base + tid + 256 * k];
    float s = ev[0] + ev[1] + ev[2] + ev[3];
    s = wred_add(s);
    if (lane == 0) red[wid] = s;
    __syncthreads();
    const float Z = red[0] + red[1] + red[2] + red[3];
    const float Zr = 1.f / ((Z == 0.f) ? 1.f : Z);
#pragma unroll
    for (int k = 0; k < 4; ++k) e_alphas[base + tid + 256 * k] = ev[k] * Zr;

    float acc;
    if (use_part) {
        acc = 0.f;
#pragma unroll
        for (int k = 0; k < 32; ++k) acc += part[(size_t)(b * 32 + k) * D_ + tid];
    } else {
        acc = out[b * D_ + tid];
    }
    out[b * D_ + tid] = acc * Zr;
}

extern "C" void kernel_launch(void* const* d_in, const int* in_sizes, int n_in,
                              void* d_out, int out_size, void* d_ws, size_t ws_size,
                              hipStream_t stream) {
    const float* x    = (const float*)d_in[0];
    const float* mask = (const float*)d_in[1];
    const float* W    = (const float*)d_in[2];
    const float* bo   = (const float*)d_in[3];
    const float* u    = (const float*)d_in[4];
    const float* Uo   = (const float*)d_in[5];

    float* out    = (float*)d_out;             // [B, 256]
    float* alphas = out + B_ * D_;             // [B, S]
    float* betas  = alphas + (size_t)B_ * S_;  // [B, S, 256]

    __bf16* Wf = (__bf16*)d_ws;                // 128 KB
    __bf16* Uf = Wf + 65536;                   // 128 KB
    float* part = (float*)(Uf + 65536);        // 4096*256*4 = 4 MB (if it fits)

    const int nblk = B_ * S_ / ROWS;           // 4096
    const size_t need = 2 * 65536 * sizeof(__bf16) + (size_t)nblk * D_ * sizeof(float);
    const int use_part = (ws_size >= need) ? 1 : 0;

    if (!use_part)
        hipMemsetAsync(out, 0, (size_t)B_ * D_ * sizeof(float), stream);
    k_prep<<<256, 256, 0, stream>>>(W, Uo, Wf, Uf);
    k_rows<<<nblk, 256, 0, stream>>>(x, mask, Wf, bo, u, Uf, alphas, betas, part, out, use_part);
    k_fin <<<B_,   256, 0, stream>>>(part, alphas, out, use_part);
}